// Round 7
// baseline (123.548 us; speedup 1.0000x reference)
//
#include <hip/hip_runtime.h>

#define F 16
#define XL 128

// bands layout in d_ws: float bands[2][5][128]
//   pass 0 = row operator (x/w), pass 1 = column operator (y/h)
//   bands[p][d][pos] = coefficient of u[pos + d - 2] in deviation at pos.
//   Out-of-range taps stored as 0 (garbage neighbor reads are annihilated).

// ---------- band construction (weights staged in LDS, no dependent global loads) ----------
#define WX1_O   0
#define WX1L_O  48
#define WX1R_O  80
#define WY1_O   112
#define WY1L_O  160
#define WY1R_O  192
#define WX2_O   224
#define WX2L_O  992
#define WX2R_O  1504
#define WY2_O   2016
#define WY2L_O  2784
#define WY2R_O  3296
#define WFC_O   3808
#define WTOT    3872

__device__ __forceinline__ float g1f_l(const float* __restrict__ w1,
                                       const float* __restrict__ w1L,
                                       const float* __restrict__ w1R,
                                       int f, int v, int wp) {
  // coefficient of u[wp] in first-order field d[f, v] (pointers into LDS)
  if (v == 0) {
    if (wp == 0) return w1L[f * 2 + 0];
    if (wp == 1) return w1L[f * 2 + 1];
    return 0.f;
  }
  if (v == XL - 1) {
    if (wp == XL - 2) return w1R[f * 2 + 0];
    if (wp == XL - 1) return w1R[f * 2 + 1];
    return 0.f;
  }
  int k = wp - (v - 1);
  return (k >= 0 && k < 3) ? w1[f * 3 + k] : 0.f;
}

__global__ __launch_bounds__(256)
void build_bands_kernel(const float* __restrict__ wX1, const float* __restrict__ wX1L,
                        const float* __restrict__ wX1R, const float* __restrict__ wY1,
                        const float* __restrict__ wY1L, const float* __restrict__ wY1R,
                        const float* __restrict__ wX2, const float* __restrict__ wX2L,
                        const float* __restrict__ wX2R, const float* __restrict__ wY2,
                        const float* __restrict__ wY2L, const float* __restrict__ wY2R,
                        const float* __restrict__ wfc, float* __restrict__ bands) {
  __shared__ float wl[WTOT];
  __shared__ float r1s[2][3], r1Ls[2][2], r1Rs[2][2];
  __shared__ float qs[2][F][3], qLs[2][F][2], qRs[2][F][2];

  const int t = threadIdx.x;
  // stage all weights into LDS (coalesced, independent loads)
  {
    const float* srcs[13] = {wX1, wX1L, wX1R, wY1, wY1L, wY1R,
                             wX2, wX2L, wX2R, wY2, wY2L, wY2R, wfc};
    const int offs[13] = {WX1_O, WX1L_O, WX1R_O, WY1_O, WY1L_O, WY1R_O,
                          WX2_O, WX2L_O, WX2R_O, WY2_O, WY2L_O, WY2R_O, WFC_O};
    const int lens[13] = {48, 32, 32, 48, 32, 32, 768, 512, 512, 768, 512, 512, 64};
#pragma unroll
    for (int a = 0; a < 13; ++a)
      for (int i = t; i < lens[a]; i += 256) wl[offs[a] + i] = srcs[a][i];
  }
  __syncthreads();

  const float* lX1  = wl + WX1_O;  const float* lX1L = wl + WX1L_O; const float* lX1R = wl + WX1R_O;
  const float* lY1  = wl + WY1_O;  const float* lY1L = wl + WY1L_O; const float* lY1R = wl + WY1R_O;
  const float* lX2  = wl + WX2_O;  const float* lX2L = wl + WX2L_O; const float* lX2R = wl + WX2R_O;
  const float* lY2  = wl + WY2_O;  const float* lY2L = wl + WY2L_O; const float* lY2R = wl + WY2R_O;
  const float* lfc  = wl + WFC_O;

  // phase 1: fc-reduced weights
  if (t < 6) {
    int p = t / 3, k = t % 3;
    const float* w1 = p ? lY1 : lX1;
    int off = p ? F : 0;
    float s = 0.f;
    for (int f = 0; f < F; ++f) s += lfc[off + f] * w1[f * 3 + k];
    r1s[p][k] = s;
  } else if (t < 10) {
    int t2 = t - 6; int p = t2 / 2, k = t2 % 2;
    const float* w1L = p ? lY1L : lX1L;
    int off = p ? F : 0;
    float s = 0.f;
    for (int f = 0; f < F; ++f) s += lfc[off + f] * w1L[f * 2 + k];
    r1Ls[p][k] = s;
  } else if (t < 14) {
    int t2 = t - 10; int p = t2 / 2, k = t2 % 2;
    const float* w1R = p ? lY1R : lX1R;
    int off = p ? F : 0;
    float s = 0.f;
    for (int f = 0; f < F; ++f) s += lfc[off + f] * w1R[f * 2 + k];
    r1Rs[p][k] = s;
  } else if (t < 14 + 96) {
    int t2 = t - 14; int p = t2 / 48; int r = t2 % 48; int fi = r / 3, k = r % 3;
    const float* w2 = p ? lY2 : lX2;
    int off = p ? 3 * F : 2 * F;
    float s = 0.f;
    for (int fo = 0; fo < F; ++fo) s += lfc[off + fo] * w2[(fo * F + fi) * 3 + k];
    qs[p][fi][k] = s;
  } else if (t < 110 + 64) {
    int t2 = t - 110; int p = t2 / 32; int r = t2 % 32; int fi = r / 2, k = r % 2;
    const float* w2L = p ? lY2L : lX2L;
    int off = p ? 3 * F : 2 * F;
    float s = 0.f;
    for (int fo = 0; fo < F; ++fo) s += lfc[off + fo] * w2L[(fo * F + fi) * 2 + k];
    qLs[p][fi][k] = s;
  } else if (t < 174 + 64) {
    int t2 = t - 174; int p = t2 / 32; int r = t2 % 32; int fi = r / 2, k = r % 2;
    const float* w2R = p ? lY2R : lX2R;
    int off = p ? 3 * F : 2 * F;
    float s = 0.f;
    for (int fo = 0; fo < F; ++fo) s += lfc[off + fo] * w2R[(fo * F + fi) * 2 + k];
    qRs[p][fi][k] = s;
  }
  __syncthreads();

  // phase 2: compose 5-tap band tables (all reads from LDS)
  int gid = blockIdx.x * 256 + t;
  if (gid >= 2 * XL * 5) return;
  const int p = gid / (XL * 5);
  const int rem = gid % (XL * 5);
  const int w = rem / 5;
  const int d = rem % 5;
  const int wp = w + d - 2;

  const float* w1  = p ? lY1  : lX1;
  const float* w1L = p ? lY1L : lX1L;
  const float* w1R = p ? lY1R : lX1R;

  float c = 0.f;
  if (wp >= 0 && wp < XL) {
    if (w == 0) {
      if (wp == 0)       c += r1Ls[p][0];
      else if (wp == 1)  c += r1Ls[p][1];
    } else if (w == XL - 1) {
      if (wp == XL - 2)      c += r1Rs[p][0];
      else if (wp == XL - 1) c += r1Rs[p][1];
    } else {
      int k = wp - (w - 1);
      if (k >= 0 && k < 3) c += r1s[p][k];
    }
    if (w == 0) {
      for (int vi = 0; vi < 2; ++vi)
        for (int fi = 0; fi < F; ++fi)
          c += qLs[p][fi][vi] * g1f_l(w1, w1L, w1R, fi, vi, wp);
    } else if (w == XL - 1) {
      for (int vi = 0; vi < 2; ++vi)
        for (int fi = 0; fi < F; ++fi)
          c += qRs[p][fi][vi] * g1f_l(w1, w1L, w1R, fi, XL - 2 + vi, wp);
    } else {
      for (int k2 = 0; k2 < 3; ++k2) {
        int v = w - 1 + k2;
        for (int fi = 0; fi < F; ++fi)
          c += qs[p][fi][k2] * g1f_l(w1, w1L, w1R, fi, v, wp);
      }
    }
  }
  bands[(p * 5 + d) * XL + w] = c;
}

// ---------- one fd iteration: 11-point cross stencil, field ping-pong ----------
// 512 blocks = 64 images x 8 row-tiles (16 rows x 128 cols), 256 threads,
// 2 blocks/CU -> 8 waves/CU. LDS tile 20x132 (halo 2, pad +4). Each thread:
// 2 rows x 4 cols. Gated by (step < fdblock) so a fixed 8-launch chain is
// correct for any fdblock in [0,8].
#define TR 16
#define LROWS 20
#define LSTRIDE 132

__global__ __launch_bounds__(256)
void fd_step_kernel(const float* __restrict__ src, float* __restrict__ dst,
                    const float* __restrict__ bands, const int* __restrict__ fdp,
                    const int step) {
  __shared__ float tile[LROWS * LSTRIDE];   // 10560 B

  const int tid = threadIdx.x;
  const int img = blockIdx.x & 63;          // same image -> same blockIdx%8 -> same XCD
  const int tb  = blockIdx.x >> 6;          // row tile 0..7
  const int R0  = TR * tb;
  const float* sp = src + img * XL * XL;

  // stage rows R0-2 .. R0+17 (clamped; clamp garbage is coeff-annihilated)
  for (int idx = tid; idx < LROWS * 32; idx += 256) {
    const int lr = idx >> 5, c4 = idx & 31;
    int gr = R0 - 2 + lr; gr = (gr < 0) ? 0 : (gr > 127 ? 127 : gr);
    const float4 v = ((const float4*)(sp + gr * XL))[c4];
    *(float4*)&tile[lr * LSTRIDE + 4 * c4] = v;
  }

  const float gate = (step < fdp[0]) ? 1.f : 0.f;
  const int q = tid & 31;            // column quad: cols 4q..4q+3
  const int rp = tid >> 3 >> 2;      // = tid >> 5, row pair 0..7
  const int gr0 = R0 + 2 * rp;

  float4 rb0, rb1, rb2, rb3, rb4; float cb0[5], cb1[5];
  rb0 = ((const float4*)(bands + 0 * XL))[q];
  rb1 = ((const float4*)(bands + 1 * XL))[q];
  rb2 = ((const float4*)(bands + 2 * XL))[q];
  rb3 = ((const float4*)(bands + 3 * XL))[q];
  rb4 = ((const float4*)(bands + 4 * XL))[q];
#pragma unroll
  for (int d = 0; d < 5; ++d) {
    cb0[d] = bands[(5 + d) * XL + gr0];
    cb1[d] = bands[(5 + d) * XL + gr0 + 1];
  }
  __syncthreads();

  const int lr = 2 + 2 * rp;         // LDS row of output row gr0
  float4 v0, v1, v2, v3, v4, v5;     // LDS rows lr-2 .. lr+3 at quad q
  v0 = *(const float4*)&tile[(lr - 2) * LSTRIDE + 4 * q];
  v1 = *(const float4*)&tile[(lr - 1) * LSTRIDE + 4 * q];
  v2 = *(const float4*)&tile[(lr + 0) * LSTRIDE + 4 * q];
  v3 = *(const float4*)&tile[(lr + 1) * LSTRIDE + 4 * q];
  v4 = *(const float4*)&tile[(lr + 2) * LSTRIDE + 4 * q];
  v5 = *(const float4*)&tile[(lr + 3) * LSTRIDE + 4 * q];
  const int cl = (q > 0) ? 4 * q - 2 : 0;        // OOB taps coeff-annihilated
  const int cr = (q < 31) ? 4 * q + 4 : 4 * q + 2;
  const float2 hl0 = *(const float2*)&tile[(lr + 0) * LSTRIDE + cl];
  const float2 hr0 = *(const float2*)&tile[(lr + 0) * LSTRIDE + cr];
  const float2 hl1 = *(const float2*)&tile[(lr + 1) * LSTRIDE + cl];
  const float2 hr1 = *(const float2*)&tile[(lr + 1) * LSTRIDE + cr];

  float4 o0, o1;
  // row gr0 (center v2; vertical v0,v1,v2,v3,v4)
  o0.x = v2.x + gate * (rb0.x * hl0.x + rb1.x * hl0.y + rb2.x * v2.x + rb3.x * v2.y + rb4.x * v2.z
                      + cb0[0] * v0.x + cb0[1] * v1.x + cb0[2] * v2.x + cb0[3] * v3.x + cb0[4] * v4.x);
  o0.y = v2.y + gate * (rb0.y * hl0.y + rb1.y * v2.x + rb2.y * v2.y + rb3.y * v2.z + rb4.y * v2.w
                      + cb0[0] * v0.y + cb0[1] * v1.y + cb0[2] * v2.y + cb0[3] * v3.y + cb0[4] * v4.y);
  o0.z = v2.z + gate * (rb0.z * v2.x + rb1.z * v2.y + rb2.z * v2.z + rb3.z * v2.w + rb4.z * hr0.x
                      + cb0[0] * v0.z + cb0[1] * v1.z + cb0[2] * v2.z + cb0[3] * v3.z + cb0[4] * v4.z);
  o0.w = v2.w + gate * (rb0.w * v2.y + rb1.w * v2.z + rb2.w * v2.w + rb3.w * hr0.x + rb4.w * hr0.y
                      + cb0[0] * v0.w + cb0[1] * v1.w + cb0[2] * v2.w + cb0[3] * v3.w + cb0[4] * v4.w);
  // row gr0+1 (center v3; vertical v1,v2,v3,v4,v5)
  o1.x = v3.x + gate * (rb0.x * hl1.x + rb1.x * hl1.y + rb2.x * v3.x + rb3.x * v3.y + rb4.x * v3.z
                      + cb1[0] * v1.x + cb1[1] * v2.x + cb1[2] * v3.x + cb1[3] * v4.x + cb1[4] * v5.x);
  o1.y = v3.y + gate * (rb0.y * hl1.y + rb1.y * v3.x + rb2.y * v3.y + rb3.y * v3.z + rb4.y * v3.w
                      + cb1[0] * v1.y + cb1[1] * v2.y + cb1[2] * v3.y + cb1[3] * v4.y + cb1[4] * v5.y);
  o1.z = v3.z + gate * (rb0.z * v3.x + rb1.z * v3.y + rb2.z * v3.z + rb3.z * v3.w + rb4.z * hr1.x
                      + cb1[0] * v1.z + cb1[1] * v2.z + cb1[2] * v3.z + cb1[3] * v4.z + cb1[4] * v5.z);
  o1.w = v3.w + gate * (rb0.w * v3.y + rb1.w * v3.z + rb2.w * v3.w + rb3.w * hr1.x + rb4.w * hr1.y
                      + cb1[0] * v1.w + cb1[1] * v2.w + cb1[2] * v3.w + cb1[3] * v4.w + cb1[4] * v5.w);

  float* dp = dst + img * XL * XL;
  ((float4*)(dp + (gr0 + 0) * XL))[q] = o0;
  ((float4*)(dp + (gr0 + 1) * XL))[q] = o1;
}

extern "C" void kernel_launch(void* const* d_in, const int* in_sizes, int n_in,
                              void* d_out, int out_size, void* d_ws, size_t ws_size,
                              hipStream_t stream) {
  const float* xInput = (const float*)d_in[0];
  const float* wX1  = (const float*)d_in[1];
  const float* wX1L = (const float*)d_in[2];
  const float* wX1R = (const float*)d_in[3];
  const float* wY1  = (const float*)d_in[4];
  const float* wY1L = (const float*)d_in[5];
  const float* wY1R = (const float*)d_in[6];
  const float* wX2  = (const float*)d_in[7];
  const float* wX2L = (const float*)d_in[8];
  const float* wX2R = (const float*)d_in[9];
  const float* wY2  = (const float*)d_in[10];
  const float* wY2L = (const float*)d_in[11];
  const float* wY2R = (const float*)d_in[12];
  const float* wfc  = (const float*)d_in[13];
  const int*   fdp  = (const int*)d_in[14];

  float* wsf   = (float*)d_ws;
  float* bands = wsf;                       // 1280 floats
  float* bufA  = wsf + (1u << 20);          // 4 MiB field
  float* bufB  = wsf + (2u << 20);          // 4 MiB field
  float* out   = (float*)d_out;

  build_bands_kernel<<<5, 256, 0, stream>>>(wX1, wX1L, wX1R, wY1, wY1L, wY1R,
                                            wX2, wX2L, wX2R, wY2, wY2L, wY2R,
                                            wfc, bands);

  // fixed 8-step chain, each step gated by (step < fdblock) in-kernel
  const float* s = xInput;
  float* d = bufA;
  for (int i = 0; i < 8; ++i) {
    if (i == 7) d = out;
    fd_step_kernel<<<512, 256, 0, stream>>>(s, d, bands, fdp, i);
    s = d;
    d = (i % 2 == 0) ? bufB : bufA;
  }
}

// Round 8
// 111.617 us; speedup vs baseline: 1.1069x; 1.1069x over previous
//
#include <hip/hip_runtime.h>

#define F 16
#define XL 128

// DPP whole-wave lane shifts (VALU pipe, no LDS). shr1: lane i <- lane i-1
// (lane 0 gets 0); shl1: lane i <- lane i+1 (lane 63 gets 0).
__device__ __forceinline__ float dpp_shr1(float x) {
  return __int_as_float(
      __builtin_amdgcn_update_dpp(0, __float_as_int(x), 0x138, 0xf, 0xf, true));
}
__device__ __forceinline__ float dpp_shl1(float x) {
  return __int_as_float(
      __builtin_amdgcn_update_dpp(0, __float_as_int(x), 0x130, 0xf, 0xf, true));
}

__device__ __forceinline__ float g1f(const float* __restrict__ w1,
                                     const float* __restrict__ w1L,
                                     const float* __restrict__ w1R,
                                     int f, int v, int wp) {
  // coefficient of u[wp] in first-order field d[f, v]
  if (v == 0) {
    if (wp == 0) return w1L[f * 2 + 0];
    if (wp == 1) return w1L[f * 2 + 1];
    return 0.f;
  }
  if (v == XL - 1) {
    if (wp == XL - 2) return w1R[f * 2 + 0];
    if (wp == XL - 1) return w1R[f * 2 + 1];
    return 0.f;
  }
  int k = wp - (v - 1);
  return (k >= 0 && k < 3) ? w1[f * 3 + k] : 0.f;
}

struct Cf {
  float rbi[5], rbe0[5], rbe1[5], rbe6[5], rbe7[5], cb0[5], cb1[5];
};

// One application of T = I + R + C on an extended col window.
// e0/e1: OLD field rows r0/r1 at cols c0+KLO-2 .. c0+KLO+OUTN+1 (OUTN+4 wide).
// o0/o1: NEW field at cols c0+KLO .. c0+KLO+OUTN-1.
// Vertical taps via DPP (rows live across lanes). Row-band coeff chosen per
// output col k: own cols 0,1,6,7 get per-col values; k in {-2,-1,8,9} are
// provably never image-boundary cols (c0 % 8 == 0) -> interior coeffs.
template <int OUTN, int KLO>
__device__ __forceinline__ void stepT(const float (&e0)[OUTN + 4], const float (&e1)[OUTN + 4],
                                      float (&o0)[OUTN], float (&o1)[OUTN], const Cf& cf) {
#pragma unroll
  for (int j = 0; j < OUTN; ++j) {
    const int k = KLO + j;
    float c0b, c1b, c2b, c3b, c4b;
    if (k == 0)      { c0b = cf.rbe0[0]; c1b = cf.rbe0[1]; c2b = cf.rbe0[2]; c3b = cf.rbe0[3]; c4b = cf.rbe0[4]; }
    else if (k == 1) { c0b = cf.rbe1[0]; c1b = cf.rbe1[1]; c2b = cf.rbe1[2]; c3b = cf.rbe1[3]; c4b = cf.rbe1[4]; }
    else if (k == 6) { c0b = cf.rbe6[0]; c1b = cf.rbe6[1]; c2b = cf.rbe6[2]; c3b = cf.rbe6[3]; c4b = cf.rbe6[4]; }
    else if (k == 7) { c0b = cf.rbe7[0]; c1b = cf.rbe7[1]; c2b = cf.rbe7[2]; c3b = cf.rbe7[3]; c4b = cf.rbe7[4]; }
    else             { c0b = cf.rbi[0];  c1b = cf.rbi[1];  c2b = cf.rbi[2];  c3b = cf.rbi[3];  c4b = cf.rbi[4];  }
    const float a0 = e0[j + 2], a1 = e1[j + 2];
    const float vm2 = dpp_shr1(a0);   // row r0-2
    const float vm1 = dpp_shr1(a1);   // row r0-1 (= r1-2)
    const float vp2 = dpp_shl1(a0);   // row r1+1 (= r0+2)
    const float vp3 = dpp_shl1(a1);   // row r1+2
    o0[j] = a0
      + c0b * e0[j] + c1b * e0[j + 1] + c2b * a0 + c3b * e0[j + 3] + c4b * e0[j + 4]
      + cf.cb0[0] * vm2 + cf.cb0[1] * vm1 + cf.cb0[2] * a0 + cf.cb0[3] * a1 + cf.cb0[4] * vp2;
    o1[j] = a1
      + c0b * e1[j] + c1b * e1[j + 1] + c2b * a1 + c3b * e1[j + 3] + c4b * e1[j + 4]
      + cf.cb1[0] * vm1 + cf.cb1[1] * a0 + cf.cb1[2] * a1 + cf.cb1[3] * vp2 + cf.cb1[4] * vp3;
  }
}

// Single fused kernel. 256 blocks = 64 images x 4 col-slabs, 512 threads =
// 8 waves x 8 cols (1 block/CU, 2 waves/SIMD). Lane z owns rows 2z,2z+1 x
// 8 cols in registers; vertical taps via DPP (wave spans all 128 rows).
// Preamble composes the 5-tap band operators in LDS (redundant per block,
// ~0.3 us). Main loop: DOUBLE-stepped trapezoid — one halo exchange +
// barrier per TWO applications of T (4 rounds for fdblock=8). Margin 16
// cols/side, corruption advances 4 cols/round.
__global__ __launch_bounds__(512, 2)
void fd_fused2_kernel(const float* __restrict__ x_in,
                      const float* __restrict__ wX1, const float* __restrict__ wX1L,
                      const float* __restrict__ wX1R, const float* __restrict__ wY1,
                      const float* __restrict__ wY1L, const float* __restrict__ wY1R,
                      const float* __restrict__ wX2, const float* __restrict__ wX2L,
                      const float* __restrict__ wX2R, const float* __restrict__ wY2,
                      const float* __restrict__ wY2L, const float* __restrict__ wY2R,
                      const float* __restrict__ wfc, const int* __restrict__ fdp,
                      float* __restrict__ x_out) {
  __shared__ float4 hb[2][8][2][2][64];       // halo: [buf][wave][L/R][row0/1][lane] = 64 KB
  __shared__ float rbl[5][XL], cbl[5][XL];    // composed band tables
  __shared__ float r1s[2][3], r1Ls[2][2], r1Rs[2][2];
  __shared__ float qs[2][F][3], qLs[2][F][2], qRs[2][F][2];

  const int tid = threadIdx.x;
  const int z = tid & 63;
  const int w = tid >> 6;
  const int n = blockIdx.x >> 2;
  const int s = blockIdx.x & 3;
  int cs0 = 32 * s - 16; if (cs0 < 0) cs0 = 0; if (cs0 > 64) cs0 = 64;
  const int c0 = cs0 + 8 * w;
  const int r0 = 2 * z, r1 = 2 * z + 1;

  // ---- stage field registers early (overlaps preamble compute) ----
  float f0[8], f1[8];
  {
    const float* img = x_in + n * XL * XL;
    const float4* a = (const float4*)(img + r0 * XL + c0);
    const float4* b = (const float4*)(img + r1 * XL + c0);
#pragma unroll
    for (int m = 0; m < 2; ++m) {
      const float4 v = a[m];
      f0[4 * m] = v.x; f0[4 * m + 1] = v.y; f0[4 * m + 2] = v.z; f0[4 * m + 3] = v.w;
      const float4 u = b[m];
      f1[4 * m] = u.x; f1[4 * m + 1] = u.y; f1[4 * m + 2] = u.z; f1[4 * m + 3] = u.w;
    }
  }

  // ---- preamble phase 1: fc-reduced weights ----
  {
    const int t = tid;
    if (t < 6) {
      int p = t / 3, k = t % 3;
      const float* w1 = p ? wY1 : wX1;
      int off = p ? F : 0;
      float sm = 0.f;
      for (int f = 0; f < F; ++f) sm += wfc[off + f] * w1[f * 3 + k];
      r1s[p][k] = sm;
    } else if (t < 10) {
      int t2 = t - 6; int p = t2 / 2, k = t2 % 2;
      const float* w1L = p ? wY1L : wX1L;
      int off = p ? F : 0;
      float sm = 0.f;
      for (int f = 0; f < F; ++f) sm += wfc[off + f] * w1L[f * 2 + k];
      r1Ls[p][k] = sm;
    } else if (t < 14) {
      int t2 = t - 10; int p = t2 / 2, k = t2 % 2;
      const float* w1R = p ? wY1R : wX1R;
      int off = p ? F : 0;
      float sm = 0.f;
      for (int f = 0; f < F; ++f) sm += wfc[off + f] * w1R[f * 2 + k];
      r1Rs[p][k] = sm;
    } else if (t < 14 + 96) {
      int t2 = t - 14; int p = t2 / 48; int r = t2 % 48; int fi = r / 3, k = r % 3;
      const float* w2 = p ? wY2 : wX2;
      int off = p ? 3 * F : 2 * F;
      float sm = 0.f;
      for (int fo = 0; fo < F; ++fo) sm += wfc[off + fo] * w2[(fo * F + fi) * 3 + k];
      qs[p][fi][k] = sm;
    } else if (t < 110 + 64) {
      int t2 = t - 110; int p = t2 / 32; int r = t2 % 32; int fi = r / 2, k = r % 2;
      const float* w2L = p ? wY2L : wX2L;
      int off = p ? 3 * F : 2 * F;
      float sm = 0.f;
      for (int fo = 0; fo < F; ++fo) sm += wfc[off + fo] * w2L[(fo * F + fi) * 2 + k];
      qLs[p][fi][k] = sm;
    } else if (t < 174 + 64) {
      int t2 = t - 174; int p = t2 / 32; int r = t2 % 32; int fi = r / 2, k = r % 2;
      const float* w2R = p ? wY2R : wX2R;
      int off = p ? 3 * F : 2 * F;
      float sm = 0.f;
      for (int fo = 0; fo < F; ++fo) sm += wfc[off + fo] * w2R[(fo * F + fi) * 2 + k];
      qRs[p][fi][k] = sm;
    }
  }
  __syncthreads();

  // ---- preamble phase 2: compose 5-tap band tables ----
  for (int e = tid; e < 2 * 5 * XL; e += 512) {
    const int pp = e / (5 * XL);
    const int rem = e % (5 * XL);
    const int ww = rem / 5;
    const int d = rem % 5;
    const int wp = ww + d - 2;
    const float* w1  = pp ? wY1  : wX1;
    const float* w1L = pp ? wY1L : wX1L;
    const float* w1R = pp ? wY1R : wX1R;
    float c = 0.f;
    if (wp >= 0 && wp < XL) {
      if (ww == 0) {
        if (wp == 0)       c += r1Ls[pp][0];
        else if (wp == 1)  c += r1Ls[pp][1];
      } else if (ww == XL - 1) {
        if (wp == XL - 2)      c += r1Rs[pp][0];
        else if (wp == XL - 1) c += r1Rs[pp][1];
      } else {
        int k = wp - (ww - 1);
        if (k >= 0 && k < 3) c += r1s[pp][k];
      }
      if (ww == 0) {
        for (int vi = 0; vi < 2; ++vi)
          for (int fi = 0; fi < F; ++fi)
            c += qLs[pp][fi][vi] * g1f(w1, w1L, w1R, fi, vi, wp);
      } else if (ww == XL - 1) {
        for (int vi = 0; vi < 2; ++vi)
          for (int fi = 0; fi < F; ++fi)
            c += qRs[pp][fi][vi] * g1f(w1, w1L, w1R, fi, XL - 2 + vi, wp);
      } else {
        for (int k2 = 0; k2 < 3; ++k2) {
          int v = ww - 1 + k2;
          for (int fi = 0; fi < F; ++fi)
            c += qs[pp][fi][k2] * g1f(w1, w1L, w1R, fi, v, wp);
        }
      }
    }
    if (pp == 0) rbl[d][ww] = c; else cbl[d][ww] = c;
  }
  __syncthreads();

  // ---- per-thread coefficient registers ----
  Cf cf;
#pragma unroll
  for (int d = 0; d < 5; ++d) {
    cf.rbi[d]  = rbl[d][64];
    cf.rbe0[d] = rbl[d][c0];
    cf.rbe1[d] = rbl[d][c0 + 1];
    cf.rbe6[d] = rbl[d][c0 + 6];
    cf.rbe7[d] = rbl[d][c0 + 7];
    cf.cb0[d]  = cbl[d][r0];
    cf.cb1[d]  = cbl[d][r1];
  }

  const int fdb = fdp[0];
  const int nd = fdb >> 1;      // double rounds
  const int odd = fdb & 1;
  const int wl = (w > 0) ? w - 1 : 0;   // clamped: slab-edge garbage stays in margin
  const int wr = (w < 7) ? w + 1 : 7;

  for (int t = 0; t < nd; ++t) {
    const int b = t & 1;
    // publish 4 edge cols per side (rows r0, r1), lane-contiguous b128
    hb[b][w][0][0][z] = make_float4(f0[0], f0[1], f0[2], f0[3]);
    hb[b][w][0][1][z] = make_float4(f1[0], f1[1], f1[2], f1[3]);
    hb[b][w][1][0][z] = make_float4(f0[4], f0[5], f0[6], f0[7]);
    hb[b][w][1][1][z] = make_float4(f1[4], f1[5], f1[6], f1[7]);
    __syncthreads();
    const float4 lA = hb[b][wl][1][0][z];   // cols c0-4..c0-1, row r0
    const float4 lB = hb[b][wl][1][1][z];   // row r1
    const float4 rA = hb[b][wr][0][0][z];   // cols c0+8..c0+11, row r0
    const float4 rB = hb[b][wr][0][1][z];   // row r1

    float e0[16], e1[16];
    e0[0] = lA.x; e0[1] = lA.y; e0[2] = lA.z; e0[3] = lA.w;
    e1[0] = lB.x; e1[1] = lB.y; e1[2] = lB.z; e1[3] = lB.w;
#pragma unroll
    for (int k = 0; k < 8; ++k) { e0[4 + k] = f0[k]; e1[4 + k] = f1[k]; }
    e0[12] = rA.x; e0[13] = rA.y; e0[14] = rA.z; e0[15] = rA.w;
    e1[12] = rB.x; e1[13] = rB.y; e1[14] = rB.z; e1[15] = rB.w;

    float t0[12], t1[12];
    stepT<12, -2>(e0, e1, t0, t1, cf);      // step A: cols c0-2..c0+9
    stepT<8, 0>(t0, t1, f0, f1, cf);        // step B: cols c0..c0+7
  }

  if (odd) {
    const int b = nd & 1;
    hb[b][w][0][0][z] = make_float4(f0[0], f0[1], f0[2], f0[3]);
    hb[b][w][0][1][z] = make_float4(f1[0], f1[1], f1[2], f1[3]);
    hb[b][w][1][0][z] = make_float4(f0[4], f0[5], f0[6], f0[7]);
    hb[b][w][1][1][z] = make_float4(f1[4], f1[5], f1[6], f1[7]);
    __syncthreads();
    const float4 lA = hb[b][wl][1][0][z];
    const float4 lB = hb[b][wl][1][1][z];
    const float4 rA = hb[b][wr][0][0][z];
    const float4 rB = hb[b][wr][0][1][z];
    float e0[12], e1[12];
    e0[0] = lA.z; e0[1] = lA.w;             // cols c0-2, c0-1
    e1[0] = lB.z; e1[1] = lB.w;
#pragma unroll
    for (int k = 0; k < 8; ++k) { e0[2 + k] = f0[k]; e1[2 + k] = f1[k]; }
    e0[10] = rA.x; e0[11] = rA.y;           // cols c0+8, c0+9
    e1[10] = rB.x; e1[11] = rB.y;
    float o0[8], o1[8];
    stepT<8, 0>(e0, e1, o0, o1, cf);
#pragma unroll
    for (int k = 0; k < 8; ++k) { f0[k] = o0[k]; f1[k] = o1[k]; }
  }

  // store: only waves whose 8 cols lie in the interior window [32s, 32s+32)
  const int rel = c0 - 32 * s;
  if (rel >= 0 && rel < 32) {
    float* outp = x_out + n * XL * XL;
    float4* o0p = (float4*)(outp + r0 * XL + c0);
    float4* o1p = (float4*)(outp + r1 * XL + c0);
#pragma unroll
    for (int m = 0; m < 2; ++m) {
      o0p[m] = make_float4(f0[4 * m], f0[4 * m + 1], f0[4 * m + 2], f0[4 * m + 3]);
      o1p[m] = make_float4(f1[4 * m], f1[4 * m + 1], f1[4 * m + 2], f1[4 * m + 3]);
    }
  }
}

extern "C" void kernel_launch(void* const* d_in, const int* in_sizes, int n_in,
                              void* d_out, int out_size, void* d_ws, size_t ws_size,
                              hipStream_t stream) {
  const float* xInput = (const float*)d_in[0];
  const float* wX1  = (const float*)d_in[1];
  const float* wX1L = (const float*)d_in[2];
  const float* wX1R = (const float*)d_in[3];
  const float* wY1  = (const float*)d_in[4];
  const float* wY1L = (const float*)d_in[5];
  const float* wY1R = (const float*)d_in[6];
  const float* wX2  = (const float*)d_in[7];
  const float* wX2L = (const float*)d_in[8];
  const float* wX2R = (const float*)d_in[9];
  const float* wY2  = (const float*)d_in[10];
  const float* wY2L = (const float*)d_in[11];
  const float* wY2R = (const float*)d_in[12];
  const float* wfc  = (const float*)d_in[13];
  const int*   fdp  = (const int*)d_in[14];

  float* out = (float*)d_out;

  fd_fused2_kernel<<<256, 512, 0, stream>>>(xInput, wX1, wX1L, wX1R, wY1, wY1L, wY1R,
                                            wX2, wX2L, wX2R, wY2, wY2L, wY2R,
                                            wfc, fdp, out);
}